// Round 1
// baseline (757.009 us; speedup 1.0000x reference)
//
#include <hip/hip_runtime.h>

#define B_ 256
#define H_ 1024
#define L_ 400
#define V_ 50257

typedef __bf16 bf16x8 __attribute__((ext_vector_type(8)));
typedef float f32x4 __attribute__((ext_vector_type(4)));

#define MFMA(a, b, c) __builtin_amdgcn_mfma_f32_16x16x32_bf16(a, b, c, 0, 0, 0)

// ---------- helpers ----------

__device__ __forceinline__ bf16x8 load8(const float* p) {
    float4 u0 = *(const float4*)p;
    float4 u1 = *(const float4*)(p + 4);
    bf16x8 r;
    r[0] = (__bf16)u0.x; r[1] = (__bf16)u0.y; r[2] = (__bf16)u0.z; r[3] = (__bf16)u0.w;
    r[4] = (__bf16)u1.x; r[5] = (__bf16)u1.y; r[6] = (__bf16)u1.z; r[7] = (__bf16)u1.w;
    return r;
}

// split f into hi (truncated bf16) + lo (bf16 of residual); hi+lo ~ f to ~2^-17
__device__ __forceinline__ void split8(const float* p, bf16x8& hi, bf16x8& lo) {
    float4 u0 = *(const float4*)p;
    float4 u1 = *(const float4*)(p + 4);
    float f[8] = {u0.x, u0.y, u0.z, u0.w, u1.x, u1.y, u1.z, u1.w};
#pragma unroll
    for (int j = 0; j < 8; ++j) {
        unsigned ui = __float_as_uint(f[j]);
        union { unsigned short s; __bf16 b; } cv;
        cv.s = (unsigned short)(ui >> 16);
        hi[j] = cv.b;
        lo[j] = (__bf16)(f[j] - __uint_as_float(ui & 0xffff0000u));
    }
}

// ---------- kernel 1: attention scores S = [x|h] @ attn_W^T  (split precision) ----------
// grid: 16 m-tiles * 25 l-tiles = 400 blocks, 128 threads (2 waves split K halves)
__global__ __launch_bounds__(128) void k_scores(
    const float* __restrict__ x, const float* __restrict__ h,
    const float* __restrict__ attn_W, float* __restrict__ S) {
    int tid = threadIdx.x, wave = tid >> 6, lane = tid & 63, li = lane & 15, g = lane >> 4;
    int bm = blockIdx.x / 25;
    int bl = blockIdx.x % 25;
    int row = bm * 16 + li;
    int colW = bl * 16 + li;
    const float* abase = wave ? h : x;  // wave0: x half (k<1024), wave1: h half
    f32x4 acc = {0.f, 0.f, 0.f, 0.f};
    for (int k = 0; k < 1024; k += 32) {
        bf16x8 ah, al;
        split8(abase + (size_t)row * H_ + k + 8 * g, ah, al);
        bf16x8 bh, bl_;
        split8(attn_W + (size_t)colW * (2 * H_) + wave * 1024 + k + 8 * g, bh, bl_);
        acc = MFMA(ah, bh, acc);
        acc = MFMA(ah, bl_, acc);
        acc = MFMA(al, bh, acc);
    }
    __shared__ float Sp[2][16][16];
#pragma unroll
    for (int r = 0; r < 4; ++r) Sp[wave][4 * g + r][li] = acc[r];
    __syncthreads();
    for (int i = tid; i < 256; i += 128) {
        int r = i >> 4, c = i & 15;
        S[(size_t)(bm * 16 + r) * L_ + bl * 16 + c] = Sp[0][r][c] + Sp[1][r][c];
    }
}

// ---------- kernel 2: softmax over L (in place on S -> P), + zero rowsum ----------
// grid 16 blocks x 256 threads; 16 threads cooperate per row
__global__ __launch_bounds__(256) void k_softmax(
    float* __restrict__ P, const float* __restrict__ attn_b, float* __restrict__ rowsum) {
    int tid = threadIdx.x;
    if (blockIdx.x == 0) rowsum[tid] = 0.0f;
    int rr = tid >> 4, c0 = tid & 15;
    int row = blockIdx.x * 16 + rr;
    float vals[25];
    float m = -1e30f;
#pragma unroll
    for (int i = 0; i < 25; ++i) {
        int c = c0 + 16 * i;
        vals[i] = P[(size_t)row * L_ + c] + attn_b[c];
        m = fmaxf(m, vals[i]);
    }
#pragma unroll
    for (int off = 8; off >= 1; off >>= 1) m = fmaxf(m, __shfl_xor(m, off));
    float s = 0.f;
#pragma unroll
    for (int i = 0; i < 25; ++i) {
        vals[i] = __expf(vals[i] - m);
        s += vals[i];
    }
#pragma unroll
    for (int off = 8; off >= 1; off >>= 1) s += __shfl_xor(s, off);
    float inv = 1.0f / s;
#pragma unroll
    for (int i = 0; i < 25; ++i) P[(size_t)row * L_ + c0 + 16 * i] = vals[i] * inv;
}

// ---------- kernel 3: attn_applied = P @ E   (M=256,N=1024,K=400 pad 416) ----------
// grid 512 (16 m x 32 n-chunks of 32), 64 threads
__global__ __launch_bounds__(64) void k_attnapply(
    const float* __restrict__ P, const float* __restrict__ E, float* __restrict__ AA) {
    int lane = threadIdx.x & 63, li = lane & 15, g = lane >> 4;
    int bm = blockIdx.x >> 5, bn = blockIdx.x & 31;
    int m0 = bm * 16, n0 = bn * 32;
    int row = m0 + li;
    f32x4 acc[2];
    f32x4 z = {0.f, 0.f, 0.f, 0.f};
    acc[0] = z; acc[1] = z;
    for (int kk = 0; kk < 416; kk += 32) {
        int k8 = kk + 8 * g;
        bf16x8 aF;
        if (k8 < L_) {
            aF = load8(P + (size_t)row * L_ + k8);
        } else {
#pragma unroll
            for (int j = 0; j < 8; ++j) aF[j] = (__bf16)0.f;
        }
#pragma unroll
        for (int t = 0; t < 2; ++t) {
            int c = n0 + t * 16 + li;
            bf16x8 bF;
#pragma unroll
            for (int j = 0; j < 8; ++j) {
                int k = k8 + j;
                if (k > L_ - 1) k = L_ - 1;  // clamped rows multiply with A==0
                bF[j] = (__bf16)E[(size_t)k * H_ + c];
            }
            acc[t] = MFMA(aF, bF, acc[t]);
        }
    }
#pragma unroll
    for (int t = 0; t < 2; ++t)
#pragma unroll
        for (int r = 0; r < 4; ++r)
            AA[(size_t)(m0 + 4 * g + r) * H_ + n0 + t * 16 + li] = acc[t][r];
}

// ---------- kernel 4: O = relu([x|AA] @ comb_W^T + comb_b) ----------
// grid 512 (16 m x 32 n-chunks of 32), 64 threads
__global__ __launch_bounds__(64) void k_combine(
    const float* __restrict__ x, const float* __restrict__ AA,
    const float* __restrict__ comb_W, const float* __restrict__ comb_b,
    float* __restrict__ O) {
    int lane = threadIdx.x & 63, li = lane & 15, g = lane >> 4;
    int bm = blockIdx.x >> 5, bn = blockIdx.x & 31;
    int m0 = bm * 16, n0 = bn * 32;
    int row = m0 + li;
    f32x4 acc[2];
    f32x4 z = {0.f, 0.f, 0.f, 0.f};
    acc[0] = z; acc[1] = z;
    for (int kk = 0; kk < 2 * H_; kk += 32) {
        const float* src = (kk < H_) ? (x + (size_t)row * H_ + kk)
                                     : (AA + (size_t)row * H_ + (kk - H_));
        bf16x8 aF = load8(src + 8 * g);
#pragma unroll
        for (int t = 0; t < 2; ++t) {
            bf16x8 bF = load8(comb_W + (size_t)(n0 + t * 16 + li) * (2 * H_) + kk + 8 * g);
            acc[t] = MFMA(aF, bF, acc[t]);
        }
    }
#pragma unroll
    for (int t = 0; t < 2; ++t) {
        int c = n0 + t * 16 + li;
        float bias = comb_b[c];
#pragma unroll
        for (int r = 0; r < 4; ++r) {
            float v = acc[t][r] + bias;
            O[(size_t)(m0 + 4 * g + r) * H_ + c] = fmaxf(v, 0.f);
        }
    }
}

// ---------- kernel 5: fused GRU (gi, gh GEMMs + gates) -> h_new ----------
// grid 512 (16 m x 32 n-chunks of 32), 64 threads
__global__ __launch_bounds__(64) void k_gru(
    const float* __restrict__ O, const float* __restrict__ h,
    const float* __restrict__ Wih, const float* __restrict__ Whh,
    const float* __restrict__ bih, const float* __restrict__ bhh,
    float* __restrict__ hnew) {
    int lane = threadIdx.x & 63, li = lane & 15, g = lane >> 4;
    int bm = blockIdx.x >> 5, bn = blockIdx.x & 31;
    int m0 = bm * 16, n0 = bn * 32;
    int row = m0 + li;
    f32x4 aIR[2], aIZ[2], aIN[2], aHR[2], aHZ[2], aHN[2];
    f32x4 z = {0.f, 0.f, 0.f, 0.f};
#pragma unroll
    for (int t = 0; t < 2; ++t) { aIR[t] = z; aIZ[t] = z; aIN[t] = z; aHR[t] = z; aHZ[t] = z; aHN[t] = z; }
    for (int kk = 0; kk < H_; kk += 32) {
        bf16x8 aO = load8(O + (size_t)row * H_ + kk + 8 * g);
        bf16x8 aH = load8(h + (size_t)row * H_ + kk + 8 * g);
#pragma unroll
        for (int t = 0; t < 2; ++t) {
            int c = n0 + t * 16 + li;
            aIR[t] = MFMA(aO, load8(Wih + (size_t)c * H_ + kk + 8 * g), aIR[t]);
            aIZ[t] = MFMA(aO, load8(Wih + (size_t)(c + 1024) * H_ + kk + 8 * g), aIZ[t]);
            aIN[t] = MFMA(aO, load8(Wih + (size_t)(c + 2048) * H_ + kk + 8 * g), aIN[t]);
            aHR[t] = MFMA(aH, load8(Whh + (size_t)c * H_ + kk + 8 * g), aHR[t]);
            aHZ[t] = MFMA(aH, load8(Whh + (size_t)(c + 1024) * H_ + kk + 8 * g), aHZ[t]);
            aHN[t] = MFMA(aH, load8(Whh + (size_t)(c + 2048) * H_ + kk + 8 * g), aHN[t]);
        }
    }
#pragma unroll
    for (int t = 0; t < 2; ++t) {
        int c = n0 + t * 16 + li;
        float bir = bih[c], biz = bih[c + 1024], bin = bih[c + 2048];
        float bhr = bhh[c], bhz = bhh[c + 1024], bhn = bhh[c + 2048];
#pragma unroll
        for (int r = 0; r < 4; ++r) {
            int b = m0 + 4 * g + r;
            float ir = aIR[t][r] + bir, iz = aIZ[t][r] + biz, in_ = aIN[t][r] + bin;
            float hr = aHR[t][r] + bhr, hz = aHZ[t][r] + bhz, hn = aHN[t][r] + bhn;
            float rg = 1.f / (1.f + __expf(-(ir + hr)));
            float zg = 1.f / (1.f + __expf(-(iz + hz)));
            float ng = tanhf(in_ + rg * hn);
            float ho = h[(size_t)b * H_ + c];
            hnew[(size_t)b * H_ + c] = (1.f - zg) * ng + zg * ho;
        }
    }
}

// ---------- kernel 6: logits = h_new @ out_W^T + out_b, + partial row sum of exp ----------
// 128x128 tile, BK=64, 256 threads (2x2 waves of 64x64), LDS-staged bf16
__global__ __launch_bounds__(256) void k_logits(
    const float* __restrict__ hnew, const float* __restrict__ Wo,
    const float* __restrict__ bo, float* __restrict__ logits,
    float* __restrict__ rowsum) {
    __shared__ alignas(16) __bf16 As[128][72];
    __shared__ alignas(16) __bf16 Bs[128][72];
    int tid = threadIdx.x, wave = tid >> 6, lane = tid & 63, li = lane & 15, g = lane >> 4;
    int bm = blockIdx.x & 1, bn = blockIdx.x >> 1;
    int m0 = bm * 128, n0 = bn * 128;
    int wm = wave >> 1, wn = wave & 1;
    int m0w = wm * 64, n0w = wn * 64;
    f32x4 acc[4][4];
    f32x4 z = {0.f, 0.f, 0.f, 0.f};
#pragma unroll
    for (int mi = 0; mi < 4; ++mi)
#pragma unroll
        for (int ni = 0; ni < 4; ++ni) acc[mi][ni] = z;

    for (int kk = 0; kk < H_; kk += 64) {
#pragma unroll
        for (int q = 0; q < 4; ++q) {
            int gid = tid + 256 * q;          // 0..1023
            int r = gid >> 3, k8 = (gid & 7) * 8;
            *(bf16x8*)&As[r][k8] = load8(hnew + (size_t)(m0 + r) * H_ + kk + k8);
            int rc = n0 + r;
            if (rc > V_ - 1) rc = V_ - 1;
            *(bf16x8*)&Bs[r][k8] = load8(Wo + (size_t)rc * H_ + kk + k8);
        }
        __syncthreads();
#pragma unroll
        for (int ks = 0; ks < 64; ks += 32) {
            bf16x8 aF[4], bF[4];
#pragma unroll
            for (int mi = 0; mi < 4; ++mi) aF[mi] = *(const bf16x8*)&As[m0w + mi * 16 + li][ks + 8 * g];
#pragma unroll
            for (int ni = 0; ni < 4; ++ni) bF[ni] = *(const bf16x8*)&Bs[n0w + ni * 16 + li][ks + 8 * g];
#pragma unroll
            for (int mi = 0; mi < 4; ++mi)
#pragma unroll
                for (int ni = 0; ni < 4; ++ni) acc[mi][ni] = MFMA(aF[mi], bF[ni], acc[mi][ni]);
        }
        __syncthreads();
    }

    float part[4][4];
#pragma unroll
    for (int mi = 0; mi < 4; ++mi)
#pragma unroll
        for (int r = 0; r < 4; ++r) part[mi][r] = 0.f;

#pragma unroll
    for (int mi = 0; mi < 4; ++mi) {
#pragma unroll
        for (int ni = 0; ni < 4; ++ni) {
            int c = n0 + n0w + ni * 16 + li;
            int cc = c > V_ - 1 ? V_ - 1 : c;
            float bias = bo[cc];
#pragma unroll
            for (int r = 0; r < 4; ++r) {
                float v = acc[mi][ni][r] + bias;
                if (c < V_) {
                    int grow = m0 + m0w + mi * 16 + 4 * g + r;
                    logits[(size_t)grow * V_ + c] = v;
                    part[mi][r] += __expf(v);  // |logit| small; no max-shift needed
                }
            }
        }
    }
#pragma unroll
    for (int mi = 0; mi < 4; ++mi)
#pragma unroll
        for (int r = 0; r < 4; ++r) {
            float p = part[mi][r];
#pragma unroll
            for (int off = 8; off >= 1; off >>= 1) p += __shfl_xor(p, off);
            if (li == mi * 4 + r)
                atomicAdd(&rowsum[m0 + m0w + mi * 16 + 4 * g + r], p);
        }
}

// ---------- kernel 7: lse ----------
__global__ __launch_bounds__(256) void k_lse(const float* __restrict__ rowsum, float* __restrict__ lse) {
    lse[threadIdx.x] = logf(rowsum[threadIdx.x]);
}

// ---------- kernel 8: logp = logits - lse[row]  (in place, float4) ----------
__global__ __launch_bounds__(256) void k_fix(float* __restrict__ logp, const float* __restrict__ lse) {
    const int total4 = (B_ * V_) / 4;  // 3216448
    for (int i = blockIdx.x * 256 + threadIdx.x; i < total4; i += gridDim.x * 256) {
        float4 v = ((float4*)logp)[i];
        int e0 = i * 4;
        int r = e0 / V_;
        int c = e0 - r * V_;
        if (c + 3 < V_) {
            float l = lse[r];
            v.x -= l; v.y -= l; v.z -= l; v.w -= l;
        } else {
            v.x -= lse[e0 / V_];
            v.y -= lse[(e0 + 1) / V_];
            v.z -= lse[(e0 + 2) / V_];
            v.w -= lse[(e0 + 3) / V_];
        }
        ((float4*)logp)[i] = v;
    }
}

// ---------- launch ----------
extern "C" void kernel_launch(void* const* d_in, const int* in_sizes, int n_in,
                              void* d_out, int out_size, void* d_ws, size_t ws_size,
                              hipStream_t stream) {
    const float* emb    = (const float*)d_in[0];
    const float* hid    = (const float*)d_in[1];
    const float* enc    = (const float*)d_in[2];
    const float* attn_W = (const float*)d_in[3];
    const float* attn_b = (const float*)d_in[4];
    const float* comb_W = (const float*)d_in[5];
    const float* comb_b = (const float*)d_in[6];
    const float* Wih    = (const float*)d_in[7];
    const float* Whh    = (const float*)d_in[8];
    const float* bih    = (const float*)d_in[9];
    const float* bhh    = (const float*)d_in[10];
    const float* Wo     = (const float*)d_in[11];
    const float* bo     = (const float*)d_in[12];

    float* out    = (float*)d_out;
    float* logits = out;                                  // [256][50257] (also scratch early)
    float* hnew   = out + (size_t)B_ * V_;                // [256][1024]
    float* P      = hnew + (size_t)B_ * H_;               // [256][400]

    // scratch inside the (not-yet-written) logits region:
    float* AA = logits;                                   // [256][1024]
    float* O  = logits + (size_t)B_ * H_;                 // [256][1024]

    float* ws     = (float*)d_ws;
    float* rowsum = ws;                                   // [256]
    float* lse    = ws + 256;                             // [256]

    k_scores<<<dim3(400), dim3(128), 0, stream>>>(emb, hid, attn_W, P);
    k_softmax<<<dim3(16), dim3(256), 0, stream>>>(P, attn_b, rowsum);
    k_attnapply<<<dim3(512), dim3(64), 0, stream>>>(P, enc, AA);
    k_combine<<<dim3(512), dim3(64), 0, stream>>>(emb, AA, comb_W, comb_b, O);
    k_gru<<<dim3(512), dim3(64), 0, stream>>>(O, hid, Wih, Whh, bih, bhh, hnew);
    k_logits<<<dim3(786), dim3(256), 0, stream>>>(hnew, Wo, bo, logits, rowsum);
    k_lse<<<dim3(1), dim3(256), 0, stream>>>(rowsum, lse);
    k_fix<<<dim3(2048), dim3(256), 0, stream>>>(logits, lse);
}

// Round 2
// 574.824 us; speedup vs baseline: 1.3169x; 1.3169x over previous
//
#include <hip/hip_runtime.h>

#define B_ 256
#define H_ 1024
#define L_ 400
#define V_ 50257

typedef __bf16 bf16x8 __attribute__((ext_vector_type(8)));
typedef __bf16 bf16x4 __attribute__((ext_vector_type(4)));
typedef float f32x4 __attribute__((ext_vector_type(4)));

#define MFMA(a, b, c) __builtin_amdgcn_mfma_f32_16x16x32_bf16(a, b, c, 0, 0, 0)

// ---------- helpers ----------

__device__ __forceinline__ bf16x8 load8(const float* p) {
    float4 u0 = *(const float4*)p;
    float4 u1 = *(const float4*)(p + 4);
    bf16x8 r;
    r[0] = (__bf16)u0.x; r[1] = (__bf16)u0.y; r[2] = (__bf16)u0.z; r[3] = (__bf16)u0.w;
    r[4] = (__bf16)u1.x; r[5] = (__bf16)u1.y; r[6] = (__bf16)u1.z; r[7] = (__bf16)u1.w;
    return r;
}

// split f into hi (truncated bf16) + lo (bf16 of residual); hi+lo ~ f to ~2^-17
__device__ __forceinline__ void split8(const float* p, bf16x8& hi, bf16x8& lo) {
    float4 u0 = *(const float4*)p;
    float4 u1 = *(const float4*)(p + 4);
    float f[8] = {u0.x, u0.y, u0.z, u0.w, u1.x, u1.y, u1.z, u1.w};
#pragma unroll
    for (int j = 0; j < 8; ++j) {
        unsigned ui = __float_as_uint(f[j]);
        union { unsigned short s; __bf16 b; } cv;
        cv.s = (unsigned short)(ui >> 16);
        hi[j] = cv.b;
        lo[j] = (__bf16)(f[j] - __uint_as_float(ui & 0xffff0000u));
    }
}

// ---------- kernel 1: attention scores S = [x|h] @ attn_W^T  (split precision) ----------
// grid 400 (16 m-tiles x 25 l-tiles), 512 threads = 8 waves, each wave a 256-wide K chunk
__global__ __launch_bounds__(512) void k_scores(
    const float* __restrict__ x, const float* __restrict__ h,
    const float* __restrict__ attn_W, float* __restrict__ S) {
    int tid = threadIdx.x, wave = tid >> 6, lane = tid & 63, li = lane & 15, g = lane >> 4;
    int bm = blockIdx.x / 25;
    int bl = blockIdx.x % 25;
    int row = bm * 16 + li;
    int colW = bl * 16 + li;
    const float* abase = (wave < 4) ? x : h;
    int koff = (wave >= 4) ? 1024 : 0;
    int k0 = (wave & 3) * 256;
    f32x4 acc = {0.f, 0.f, 0.f, 0.f};
    for (int k = k0; k < k0 + 256; k += 32) {
        bf16x8 ah, al;
        split8(abase + (size_t)row * H_ + k + 8 * g, ah, al);
        bf16x8 bh, bl_;
        split8(attn_W + (size_t)colW * (2 * H_) + koff + k + 8 * g, bh, bl_);
        acc = MFMA(ah, bh, acc);
        acc = MFMA(ah, bl_, acc);
        acc = MFMA(al, bh, acc);
    }
    __shared__ float Sp[8][16][16];
#pragma unroll
    for (int r = 0; r < 4; ++r) Sp[wave][4 * g + r][li] = acc[r];
    __syncthreads();
    if (tid < 256) {
        int r = tid >> 4, c = tid & 15;
        float s = 0.f;
#pragma unroll
        for (int w = 0; w < 8; ++w) s += Sp[w][r][c];
        S[(size_t)(bm * 16 + r) * L_ + bl * 16 + c] = s;
    }
}

// ---------- kernel 2: softmax over L (in place on S -> P), + zero rowsum ----------
__global__ __launch_bounds__(256) void k_softmax(
    float* __restrict__ P, const float* __restrict__ attn_b, float* __restrict__ rowsum) {
    int tid = threadIdx.x;
    if (blockIdx.x == 0) rowsum[tid] = 0.0f;
    int rr = tid >> 4, c0 = tid & 15;
    int row = blockIdx.x * 16 + rr;
    float vals[25];
    float m = -1e30f;
#pragma unroll
    for (int i = 0; i < 25; ++i) {
        int c = c0 + 16 * i;
        vals[i] = P[(size_t)row * L_ + c] + attn_b[c];
        m = fmaxf(m, vals[i]);
    }
#pragma unroll
    for (int off = 8; off >= 1; off >>= 1) m = fmaxf(m, __shfl_xor(m, off));
    float s = 0.f;
#pragma unroll
    for (int i = 0; i < 25; ++i) {
        vals[i] = __expf(vals[i] - m);
        s += vals[i];
    }
#pragma unroll
    for (int off = 8; off >= 1; off >>= 1) s += __shfl_xor(s, off);
    float inv = 1.0f / s;
#pragma unroll
    for (int i = 0; i < 25; ++i) P[(size_t)row * L_ + c0 + 16 * i] = vals[i] * inv;
}

// ---------- kernel 3: transpose encoder_states -> Et[1024][448] bf16 (zero-padded) ----------
// grid 112 = 7 r-tiles (448) x 16 c-tiles (1024), 256 threads
__global__ __launch_bounds__(256) void k_transE(
    const float* __restrict__ E, __bf16* __restrict__ Et) {
    int rt = blockIdx.x >> 4, ct = blockIdx.x & 15;
    __shared__ __bf16 T[64][72];
    int tid = threadIdx.x;
#pragma unroll
    for (int q = 0; q < 4; ++q) {
        int s = tid + 256 * q;            // 0..1023
        int r = s >> 4, c4 = (s & 15) * 4;
        int er = rt * 64 + r;
        float4 v = {0.f, 0.f, 0.f, 0.f};
        if (er < L_) v = *(const float4*)(E + (size_t)er * H_ + ct * 64 + c4);
        T[r][c4 + 0] = (__bf16)v.x;
        T[r][c4 + 1] = (__bf16)v.y;
        T[r][c4 + 2] = (__bf16)v.z;
        T[r][c4 + 3] = (__bf16)v.w;
    }
    __syncthreads();
#pragma unroll
    for (int q = 0; q < 4; ++q) {
        int s = tid + 256 * q;
        int c = s >> 4, r4 = (s & 15) * 4;  // c: Et row within tile; r4: Et col group
        bf16x4 o;
#pragma unroll
        for (int j = 0; j < 4; ++j) o[j] = T[r4 + j][c];
        *(bf16x4*)(Et + (size_t)(ct * 64 + c) * 448 + rt * 64 + r4) = o;
    }
}

// ---------- kernel 4: attn_applied = P @ E  via Et   (M=256,N=1024,K=448 padded) ----------
// tile 128x64, 256 threads (4 waves 2x2), grid 32
__global__ __launch_bounds__(256) void k_attnapply(
    const float* __restrict__ P, const __bf16* __restrict__ Et, float* __restrict__ AA) {
    __shared__ __bf16 As[128][72];
    __shared__ __bf16 Bs[64][72];
    int tid = threadIdx.x, wave = tid >> 6, lane = tid & 63, li = lane & 15, g = lane >> 4;
    int bm = blockIdx.x & 1, bn = blockIdx.x >> 1;   // bn 0..15
    int m0 = bm * 128, n0 = bn * 64;
    int wm = wave >> 1, wn = wave & 1;
    int m0w = wm * 64, n0w = wn * 32;
    f32x4 acc[4][2];
    f32x4 z = {0.f, 0.f, 0.f, 0.f};
#pragma unroll
    for (int mi = 0; mi < 4; ++mi) { acc[mi][0] = z; acc[mi][1] = z; }
    for (int kk = 0; kk < 448; kk += 64) {
#pragma unroll
        for (int q = 0; q < 4; ++q) {
            int s = tid + 256 * q;            // A slots: 128*8
            int r = s >> 3, o = s & 7;
            int k8 = kk + o * 8;
            if (k8 < L_) {
                *(bf16x8*)&As[r][o * 8] = load8(P + (size_t)(m0 + r) * L_ + k8);
            } else {
                bf16x8 zf;
#pragma unroll
                for (int j = 0; j < 8; ++j) zf[j] = (__bf16)0.f;
                *(bf16x8*)&As[r][o * 8] = zf;
            }
        }
#pragma unroll
        for (int q = 0; q < 2; ++q) {
            int s = tid + 256 * q;            // B slots: 64*8
            int r = s >> 3, o = s & 7;
            *(bf16x8*)&Bs[r][o * 8] = *(const bf16x8*)(Et + (size_t)(n0 + r) * 448 + kk + o * 8);
        }
        __syncthreads();
#pragma unroll
        for (int ks = 0; ks < 64; ks += 32) {
            bf16x8 aF[4], bF[2];
#pragma unroll
            for (int mi = 0; mi < 4; ++mi) aF[mi] = *(const bf16x8*)&As[m0w + mi * 16 + li][ks + 8 * g];
#pragma unroll
            for (int ni = 0; ni < 2; ++ni) bF[ni] = *(const bf16x8*)&Bs[n0w + ni * 16 + li][ks + 8 * g];
#pragma unroll
            for (int mi = 0; mi < 4; ++mi)
#pragma unroll
                for (int ni = 0; ni < 2; ++ni) acc[mi][ni] = MFMA(aF[mi], bF[ni], acc[mi][ni]);
        }
        __syncthreads();
    }
#pragma unroll
    for (int mi = 0; mi < 4; ++mi)
#pragma unroll
        for (int ni = 0; ni < 2; ++ni)
#pragma unroll
            for (int r = 0; r < 4; ++r)
                AA[(size_t)(m0 + m0w + mi * 16 + 4 * g + r) * H_ + n0 + n0w + ni * 16 + li] = acc[mi][ni][r];
}

// ---------- kernel 5: O = relu([x|AA] @ comb_W^T + comb_b) ----------
// tile 128x64, grid 32, K=2048
__global__ __launch_bounds__(256) void k_combine(
    const float* __restrict__ x, const float* __restrict__ AA,
    const float* __restrict__ comb_W, const float* __restrict__ comb_b,
    float* __restrict__ O) {
    __shared__ __bf16 As[128][72];
    __shared__ __bf16 Bs[64][72];
    int tid = threadIdx.x, wave = tid >> 6, lane = tid & 63, li = lane & 15, g = lane >> 4;
    int bm = blockIdx.x & 1, bn = blockIdx.x >> 1;
    int m0 = bm * 128, n0 = bn * 64;
    int wm = wave >> 1, wn = wave & 1;
    int m0w = wm * 64, n0w = wn * 32;
    f32x4 acc[4][2];
    f32x4 z = {0.f, 0.f, 0.f, 0.f};
#pragma unroll
    for (int mi = 0; mi < 4; ++mi) { acc[mi][0] = z; acc[mi][1] = z; }
    for (int kk = 0; kk < 2 * H_; kk += 64) {
        const float* Abase = (kk < H_) ? x : AA;
        int ko = (kk < H_) ? kk : (kk - H_);
#pragma unroll
        for (int q = 0; q < 4; ++q) {
            int s = tid + 256 * q;
            int r = s >> 3, o = s & 7;
            *(bf16x8*)&As[r][o * 8] = load8(Abase + (size_t)(m0 + r) * H_ + ko + o * 8);
        }
#pragma unroll
        for (int q = 0; q < 2; ++q) {
            int s = tid + 256 * q;
            int r = s >> 3, o = s & 7;
            *(bf16x8*)&Bs[r][o * 8] = load8(comb_W + (size_t)(n0 + r) * (2 * H_) + kk + o * 8);
        }
        __syncthreads();
#pragma unroll
        for (int ks = 0; ks < 64; ks += 32) {
            bf16x8 aF[4], bF[2];
#pragma unroll
            for (int mi = 0; mi < 4; ++mi) aF[mi] = *(const bf16x8*)&As[m0w + mi * 16 + li][ks + 8 * g];
#pragma unroll
            for (int ni = 0; ni < 2; ++ni) bF[ni] = *(const bf16x8*)&Bs[n0w + ni * 16 + li][ks + 8 * g];
#pragma unroll
            for (int mi = 0; mi < 4; ++mi)
#pragma unroll
                for (int ni = 0; ni < 2; ++ni) acc[mi][ni] = MFMA(aF[mi], bF[ni], acc[mi][ni]);
        }
        __syncthreads();
    }
#pragma unroll
    for (int ni = 0; ni < 2; ++ni) {
        int c = n0 + n0w + ni * 16 + li;
        float bias = comb_b[c];
#pragma unroll
        for (int mi = 0; mi < 4; ++mi)
#pragma unroll
            for (int r = 0; r < 4; ++r) {
                float v = acc[mi][ni][r] + bias;
                O[(size_t)(m0 + m0w + mi * 16 + 4 * g + r) * H_ + c] = fmaxf(v, 0.f);
            }
    }
}

// ---------- kernel 6: gi = O@Wih^T, gh = h@Whh^T as one virtual GEMM (N=6144) ----------
// tile 128x64, grid 192 = 2 m x 96 n, 256 threads
__global__ __launch_bounds__(256) void k_gigh(
    const float* __restrict__ O, const float* __restrict__ h,
    const float* __restrict__ Wih, const float* __restrict__ Whh,
    float* __restrict__ gi, float* __restrict__ gh) {
    __shared__ __bf16 As[128][72];
    __shared__ __bf16 Bs[64][72];
    int tid = threadIdx.x, wave = tid >> 6, lane = tid & 63, li = lane & 15, g = lane >> 4;
    int bm = blockIdx.x & 1, bn = blockIdx.x >> 1;   // bn 0..95
    int n0v = bn * 64;
    int half = (n0v >= 3072) ? 1 : 0;
    int n0 = n0v - 3072 * half;
    const float* A = half ? h : O;
    const float* W = half ? Whh : Wih;
    float* out = half ? gh : gi;
    int m0 = bm * 128;
    int wm = wave >> 1, wn = wave & 1;
    int m0w = wm * 64, n0w = wn * 32;
    f32x4 acc[4][2];
    f32x4 z = {0.f, 0.f, 0.f, 0.f};
#pragma unroll
    for (int mi = 0; mi < 4; ++mi) { acc[mi][0] = z; acc[mi][1] = z; }
    for (int kk = 0; kk < H_; kk += 64) {
#pragma unroll
        for (int q = 0; q < 4; ++q) {
            int s = tid + 256 * q;
            int r = s >> 3, o = s & 7;
            *(bf16x8*)&As[r][o * 8] = load8(A + (size_t)(m0 + r) * H_ + kk + o * 8);
        }
#pragma unroll
        for (int q = 0; q < 2; ++q) {
            int s = tid + 256 * q;
            int r = s >> 3, o = s & 7;
            *(bf16x8*)&Bs[r][o * 8] = load8(W + (size_t)(n0 + r) * H_ + kk + o * 8);
        }
        __syncthreads();
#pragma unroll
        for (int ks = 0; ks < 64; ks += 32) {
            bf16x8 aF[4], bF[2];
#pragma unroll
            for (int mi = 0; mi < 4; ++mi) aF[mi] = *(const bf16x8*)&As[m0w + mi * 16 + li][ks + 8 * g];
#pragma unroll
            for (int ni = 0; ni < 2; ++ni) bF[ni] = *(const bf16x8*)&Bs[n0w + ni * 16 + li][ks + 8 * g];
#pragma unroll
            for (int mi = 0; mi < 4; ++mi)
#pragma unroll
                for (int ni = 0; ni < 2; ++ni) acc[mi][ni] = MFMA(aF[mi], bF[ni], acc[mi][ni]);
        }
        __syncthreads();
    }
#pragma unroll
    for (int mi = 0; mi < 4; ++mi)
#pragma unroll
        for (int ni = 0; ni < 2; ++ni)
#pragma unroll
            for (int r = 0; r < 4; ++r)
                out[(size_t)(m0 + m0w + mi * 16 + 4 * g + r) * 3072 + n0 + n0w + ni * 16 + li] = acc[mi][ni][r];
}

// ---------- kernel 7: GRU gates (elementwise) ----------
__global__ __launch_bounds__(256) void k_gates(
    const float* __restrict__ gi, const float* __restrict__ gh,
    const float* __restrict__ h, const float* __restrict__ bih,
    const float* __restrict__ bhh, float* __restrict__ hnew) {
    int idx = blockIdx.x * 256 + threadIdx.x;   // 0..262143
    int b = idx >> 10, c = idx & 1023;
    size_t base = (size_t)b * 3072 + c;
    float ir = gi[base]        + bih[c];
    float iz = gi[base + 1024] + bih[c + 1024];
    float in_ = gi[base + 2048] + bih[c + 2048];
    float hr = gh[base]        + bhh[c];
    float hz = gh[base + 1024] + bhh[c + 1024];
    float hn = gh[base + 2048] + bhh[c + 2048];
    float rg = 1.f / (1.f + __expf(-(ir + hr)));
    float zg = 1.f / (1.f + __expf(-(iz + hz)));
    float ng = tanhf(in_ + rg * hn);
    float ho = h[idx];
    hnew[idx] = (1.f - zg) * ng + zg * ho;
}

// ---------- kernel 8: logits = h_new @ out_W^T + out_b, + partial exp row sums ----------
// tile M=256 x N=64 (4 waves stacked on M), grid 786 n-tiles; each Wo row read ONCE
__global__ __launch_bounds__(256) void k_logits(
    const float* __restrict__ hnew, const float* __restrict__ Wo,
    const float* __restrict__ bo, float* __restrict__ logits,
    float* __restrict__ rowsum) {
    __shared__ __bf16 As[256][72];
    __shared__ __bf16 Bs[64][72];
    int tid = threadIdx.x, wave = tid >> 6, lane = tid & 63, li = lane & 15, g = lane >> 4;
    int n0 = blockIdx.x * 64;
    int m0w = wave * 64;
    f32x4 acc[4][4];
    f32x4 z = {0.f, 0.f, 0.f, 0.f};
#pragma unroll
    for (int mi = 0; mi < 4; ++mi)
#pragma unroll
        for (int ni = 0; ni < 4; ++ni) acc[mi][ni] = z;

    for (int kk = 0; kk < H_; kk += 64) {
#pragma unroll
        for (int q = 0; q < 8; ++q) {
            int s = tid + 256 * q;            // A slots: 256*8
            int r = s >> 3, o = s & 7;
            *(bf16x8*)&As[r][o * 8] = load8(hnew + (size_t)r * H_ + kk + o * 8);
        }
#pragma unroll
        for (int q = 0; q < 2; ++q) {
            int s = tid + 256 * q;            // B slots: 64*8
            int r = s >> 3, o = s & 7;
            int rc = n0 + r;
            if (rc > V_ - 1) rc = V_ - 1;
            *(bf16x8*)&Bs[r][o * 8] = load8(Wo + (size_t)rc * H_ + kk + o * 8);
        }
        __syncthreads();
#pragma unroll
        for (int ks = 0; ks < 64; ks += 32) {
            bf16x8 aF[4], bF[4];
#pragma unroll
            for (int mi = 0; mi < 4; ++mi) aF[mi] = *(const bf16x8*)&As[m0w + mi * 16 + li][ks + 8 * g];
#pragma unroll
            for (int ni = 0; ni < 4; ++ni) bF[ni] = *(const bf16x8*)&Bs[ni * 16 + li][ks + 8 * g];
#pragma unroll
            for (int mi = 0; mi < 4; ++mi)
#pragma unroll
                for (int ni = 0; ni < 4; ++ni) acc[mi][ni] = MFMA(aF[mi], bF[ni], acc[mi][ni]);
        }
        __syncthreads();
    }

    float part[4][4];
#pragma unroll
    for (int mi = 0; mi < 4; ++mi)
#pragma unroll
        for (int r = 0; r < 4; ++r) part[mi][r] = 0.f;

#pragma unroll
    for (int mi = 0; mi < 4; ++mi) {
#pragma unroll
        for (int ni = 0; ni < 4; ++ni) {
            int c = n0 + ni * 16 + li;
            int cc = c > V_ - 1 ? V_ - 1 : c;
            float bias = bo[cc];
#pragma unroll
            for (int r = 0; r < 4; ++r) {
                float v = acc[mi][ni][r] + bias;
                if (c < V_) {
                    int grow = m0w + mi * 16 + 4 * g + r;
                    logits[(size_t)grow * V_ + c] = v;
                    part[mi][r] += __expf(v);
                }
            }
        }
    }
#pragma unroll
    for (int mi = 0; mi < 4; ++mi)
#pragma unroll
        for (int r = 0; r < 4; ++r) {
            float p = part[mi][r];
#pragma unroll
            for (int off = 8; off >= 1; off >>= 1) p += __shfl_xor(p, off);
            if (li == mi * 4 + r)
                atomicAdd(&rowsum[m0w + mi * 16 + 4 * g + r], p);
        }
}

// ---------- kernel 9: lse ----------
__global__ __launch_bounds__(256) void k_lse(const float* __restrict__ rowsum, float* __restrict__ lse) {
    lse[threadIdx.x] = logf(rowsum[threadIdx.x]);
}

// ---------- kernel 10: logp = logits - lse[row]  (in place, float4) ----------
__global__ __launch_bounds__(256) void k_fix(float* __restrict__ logp, const float* __restrict__ lse) {
    const int total4 = (B_ * V_) / 4;  // 3216448
    for (int i = blockIdx.x * 256 + threadIdx.x; i < total4; i += gridDim.x * 256) {
        float4 v = ((float4*)logp)[i];
        int e0 = i * 4;
        int r = e0 / V_;
        int c = e0 - r * V_;
        if (c + 3 < V_) {
            float l = lse[r];
            v.x -= l; v.y -= l; v.z -= l; v.w -= l;
        } else {
            v.x -= lse[e0 / V_];
            v.y -= lse[(e0 + 1) / V_];
            v.z -= lse[(e0 + 2) / V_];
            v.w -= lse[(e0 + 3) / V_];
        }
        ((float4*)logp)[i] = v;
    }
}

// ---------- launch ----------
extern "C" void kernel_launch(void* const* d_in, const int* in_sizes, int n_in,
                              void* d_out, int out_size, void* d_ws, size_t ws_size,
                              hipStream_t stream) {
    const float* emb    = (const float*)d_in[0];
    const float* hid    = (const float*)d_in[1];
    const float* enc    = (const float*)d_in[2];
    const float* attn_W = (const float*)d_in[3];
    const float* attn_b = (const float*)d_in[4];
    const float* comb_W = (const float*)d_in[5];
    const float* comb_b = (const float*)d_in[6];
    const float* Wih    = (const float*)d_in[7];
    const float* Whh    = (const float*)d_in[8];
    const float* bih    = (const float*)d_in[9];
    const float* bhh    = (const float*)d_in[10];
    const float* Wo     = (const float*)d_in[11];
    const float* bo     = (const float*)d_in[12];

    float* out    = (float*)d_out;
    float* logits = out;                                  // [256][50257]
    float* hnew   = out + (size_t)B_ * V_;                // [256][1024]
    float* P      = hnew + (size_t)B_ * H_;               // [256][400]

    // scratch inside the (not-yet-written) logits region (dead before k_logits):
    float*  AA = logits;                                  // 262144 floats
    float*  O  = logits + 262144;                         // 262144 floats
    float*  gi = logits + 524288;                         // 786432 floats
    float*  gh = logits + 1310720;                        // 786432 floats
    __bf16* Et = (__bf16*)(logits + 2097152);             // 1024*448 bf16

    float* ws     = (float*)d_ws;
    float* rowsum = ws;                                   // [256]
    float* lse    = ws + 256;                             // [256]

    k_scores  <<<dim3(400),  dim3(512), 0, stream>>>(emb, hid, attn_W, P);
    k_softmax <<<dim3(16),   dim3(256), 0, stream>>>(P, attn_b, rowsum);
    k_transE  <<<dim3(112),  dim3(256), 0, stream>>>(enc, Et);
    k_attnapply<<<dim3(32),  dim3(256), 0, stream>>>(P, Et, AA);
    k_combine <<<dim3(32),   dim3(256), 0, stream>>>(emb, AA, comb_W, comb_b, O);
    k_gigh    <<<dim3(192),  dim3(256), 0, stream>>>(O, hid, Wih, Whh, gi, gh);
    k_gates   <<<dim3(1024), dim3(256), 0, stream>>>(gi, gh, hid, bih, bhh, hnew);
    k_logits  <<<dim3(786),  dim3(256), 0, stream>>>(hnew, Wo, bo, logits, rowsum);
    k_lse     <<<dim3(1),    dim3(256), 0, stream>>>(rowsum, lse);
    k_fix     <<<dim3(2048), dim3(256), 0, stream>>>(logits, lse);
}